// Round 6
// baseline (284.993 us; speedup 1.0000x reference)
//
#include <hip/hip_runtime.h>
#include <hip/hip_bf16.h>
#include <stdint.h>
#include <stddef.h>

typedef __attribute__((ext_vector_type(8))) short short8;
typedef __attribute__((ext_vector_type(4))) float f32x4;
typedef unsigned short ushort_t;

#define NHEADS 16
#define HD 32
#define NQ 740
#define NB 16
#define MROWS (NB*NQ)       // 11840
#define CD 512
#define KDIM 512
#define VSTRIDE 768         // v^T row stride
#define NQT 48              // padded q-tile slots for biasT
#define PTS 36              // P^T stride in bf16 elems
#define QS2 0.2550400865f   // hd^-0.5 * log2(e)
#define LOG2E 1.4426950409f
#define NEG_BIG -43000.0f   // log2e-scaled mask; v_exp_f32 flushes to 0

static __device__ __forceinline__ void gld_lds16(const void* g, void* l) {
    __builtin_amdgcn_global_load_lds((const __attribute__((address_space(1))) void*)g,
                                     (__attribute__((address_space(3))) void*)l,
                                     16, 0, 0);
}

static __device__ __forceinline__ float ldf(const void* p, int i, int fl) {
    return fl ? ((const float*)p)[i] : (float)((const __hip_bfloat16*)p)[i];
}
static __device__ __forceinline__ ushort_t f2bf(float f) {
    __hip_bfloat16 h(f);
    return *reinterpret_cast<ushort_t*>(&h);
}
static __device__ __forceinline__ float fexp2(float x) {
#if __has_builtin(__builtin_amdgcn_exp2f)
    return __builtin_amdgcn_exp2f(x);
#else
    return exp2f(x);
#endif
}
static __device__ __forceinline__ f32x4 bias4(const __hip_bfloat16* p) {
    uint2 u = *(const uint2*)(const void*)p;
    f32x4 c;
    c[0] = __uint_as_float(u.x << 16);
    c[1] = __uint_as_float(u.x & 0xFFFF0000u);
    c[2] = __uint_as_float(u.y << 16);
    c[3] = __uint_as_float(u.y & 0xFFFF0000u);
    return c;
}
static __device__ __forceinline__ void pkstore(__hip_bfloat16* dst, f32x4 c) {
    __hip_bfloat162* d = (__hip_bfloat162*)dst;
    d[0] = __float22bfloat162_rn(make_float2(c[0], c[1]));
    d[1] = __float22bfloat162_rn(make_float2(c[2], c[3]));
}
static __device__ __forceinline__ uint2 pk4(float a, float b, float c, float d) {
    __hip_bfloat162 p01 = __float22bfloat162_rn(make_float2(a, b));
    __hip_bfloat162 p23 = __float22bfloat162_rn(make_float2(c, d));
    uint2 u;
    u.x = *reinterpret_cast<unsigned int*>(&p01);
    u.y = *reinterpret_cast<unsigned int*>(&p23);
    return u;
}

// ------------- dtype sniff: fp32 arrays have uniform low-16 mantissa bits ----
__global__ __launch_bounds__(64) void sniff_k(const unsigned int* __restrict__ w,
                                              int* __restrict__ flag) {
    int cnt = 0;
    for (int i = threadIdx.x; i < 1024; i += 64) {
        unsigned int e = (w[i] >> 7) & 0xFFu;
        cnt += (e > 135u) ? 1 : 0;
    }
    #pragma unroll
    for (int d = 1; d < 64; d <<= 1) cnt += __shfl_xor(cnt, d);
    if (threadIdx.x == 0) *flag = (cnt > 16) ? 1 : 0;
}

// ------------- x normalization: fp32->bf16 (vectorized) or bf16 copy ---------
__global__ __launch_bounds__(256) void convx_k(const void* __restrict__ src,
                                               ushort4* __restrict__ dst,
                                               int nquads, const int* __restrict__ flag) {
    int i = blockIdx.x * 256 + threadIdx.x;
    if (i >= nquads) return;
    if (*flag) {
        float4 v = ((const float4*)src)[i];
        ushort4 o;
        o.x = f2bf(v.x); o.y = f2bf(v.y); o.z = f2bf(v.z); o.w = f2bf(v.w);
        dst[i] = o;
    } else {
        dst[i] = ((const ushort4*)src)[i];
    }
}

// ---------------- transpose + convert (for B^T weight layouts) ----------------
__global__ __launch_bounds__(256) void transpose_k(const void* __restrict__ src,
                                                   __hip_bfloat16* __restrict__ dst,
                                                   int R, int C, const int* __restrict__ flag) {
    __shared__ __hip_bfloat16 tile[32][33];
    const int fl = *flag;
    int bx = blockIdx.x * 32;   // col base in src
    int by = blockIdx.y * 32;   // row base in src
    int tx = threadIdx.x;
    for (int r = threadIdx.y; r < 32; r += 8)
        tile[r][tx] = __hip_bfloat16(ldf(src, (by + r) * C + bx + tx, fl));
    __syncthreads();
    for (int r = threadIdx.y; r < 32; r += 8)
        dst[(size_t)(bx + r) * R + by + tx] = tile[tx][r];
}

// ------- bias * log2e in MFMA-C layout: [hh][qt(48)][col 768][row 16] bf16 ----
__global__ __launch_bounds__(256) void biasT_k(
    const void* __restrict__ btT,    // bias_table_target [1849][16]
    const void* __restrict__ btt,    // bias_table_temp   [961][16]
    const void* __restrict__ ttab,   // temp_target_table [16][484]
    const void* __restrict__ tgtab,  // target_temp_table [16][256]
    const void* __restrict__ ttln,   // temp_target_line  [16][256]
    const void* __restrict__ tgln,   // target_temp_line  [16][484]
    __hip_bfloat16* __restrict__ biasT, const int* __restrict__ flag) {
    const int fl = *flag;
    const int blk = blockIdx.x;          // hh*48 + qt
    const int hh = blk / NQT;
    const int qt = blk - hh * NQT;
    for (int idx = threadIdx.x; idx < 768 * 4; idx += 256) {
        const int c = idx >> 2;          // key col
        const int rg = idx & 3;          // row group (4 rows)
        ushort4 o;
        ushort_t* op = (ushort_t*)&o;
        #pragma unroll
        for (int r = 0; r < 4; ++r) {
            int i = qt * 16 + rg * 4 + r; if (i > NQ - 1) i = NQ - 1;
            float v;
            if (c >= NQ) {
                v = NEG_BIG;
            } else if (i < 256) {
                if (c < 256) {
                    int t = ((i >> 4) - (c >> 4) + 15) * 31 + ((i & 15) - (c & 15) + 15);
                    v = ldf(btt, t * 16 + hh, fl) * LOG2E;
                } else {
                    v = (ldf(tgtab, hh * 256 + i, fl) + ldf(tgln, hh * 484 + (c - 256), fl)) * LOG2E;
                }
            } else {
                int ii = i - 256;
                if (c < 256) {
                    v = (ldf(ttab, hh * 484 + ii, fl) + ldf(ttln, hh * 256 + c, fl)) * LOG2E;
                } else {
                    int jj = c - 256;
                    int a = ii / 22, b2 = ii - a * 22;
                    int a2 = jj / 22, b3 = jj - a2 * 22;
                    int t = (a - a2 + 21) * 43 + (b2 - b3 + 21);
                    v = ldf(btT, t * 16 + hh, fl) * LOG2E;
                }
            }
            op[r] = f2bf(v);
        }
        ((ushort4*)biasT)[((size_t)blk * 768 + c) * 4 + rg] = o;
    }
}

// ------- qkv GEMM: 256x128 tile, 4 waves (each 64 rows x ALL 128 cols) -------
// 32 MFMA per wave per barrier (4x the 128x128 version) -> amortizes the
// vmcnt(0)+barrier drain that made the old kernel 6.7% MfmaUtil.
// Epilogue scatters q/k ([bh][nn][d], 32B segments) and v^T packed 8B stores.
__global__ __launch_bounds__(256) void gemm_qkv(
    const __hip_bfloat16* __restrict__ A,
    const __hip_bfloat16* __restrict__ Bt,
    const void* __restrict__ biasv,
    __hip_bfloat16* __restrict__ Qw,
    __hip_bfloat16* __restrict__ Kw,
    __hip_bfloat16* __restrict__ Vtw,
    const int* __restrict__ flag) {
    __shared__ __attribute__((aligned(16))) short sA[256 * 32];   // 16 KB
    __shared__ __attribute__((aligned(16))) short sB[128 * 32];   // 8 KB
    const int tid = threadIdx.x;
    const int lane = tid & 63;
    const int wv = tid >> 6;             // 0..3: 64-row group
    const int lr = lane & 15, kc = lane >> 4;
    const int m0 = blockIdx.x * 256;
    const int n0 = blockIdx.y * 128;
    const int fl = *flag;
    const int M = MROWS;

    f32x4 acc[4][8] = {};

    for (int k0 = 0; k0 < KDIM; k0 += 32) {
        #pragma unroll
        for (int it = 0; it < 6; ++it) {
            int idx = it * 256 + tid;            // 16B unit index, 0..1535
            if (idx < 1024) {                    // A: 256 rows x 4 units
                int r = idx >> 2, c = idx & 3;
                int gr = m0 + r; if (gr > M - 1) gr = M - 1;
                gld_lds16(A + (size_t)gr * KDIM + k0 + c * 8, (char*)sA + idx * 16);
            } else {                             // B: 128 rows x 4 units
                int u = idx - 1024;
                int r = u >> 2, c = u & 3;
                gld_lds16(Bt + (size_t)(n0 + r) * KDIM + k0 + c * 8, (char*)sB + u * 16);
            }
        }
        __syncthreads();
        short8 af[4], bfr[8];
        #pragma unroll
        for (int t = 0; t < 4; ++t)
            af[t] = *(const short8*)&sA[(wv * 64 + t * 16 + lr) * 32 + kc * 8];
        #pragma unroll
        for (int t = 0; t < 8; ++t)
            bfr[t] = *(const short8*)&sB[(t * 16 + lr) * 32 + kc * 8];
        #pragma unroll
        for (int i = 0; i < 4; ++i)
            #pragma unroll
            for (int j = 0; j < 8; ++j)
                acc[i][j] = __builtin_amdgcn_mfma_f32_16x16x32_bf16(af[i], bfr[j], acc[i][j], 0, 0, 0);
        __syncthreads();
    }

    #pragma unroll
    for (int j = 0; j < 8; ++j) {
        int gn = n0 + j * 16 + lr;
        float bv = ldf(biasv, gn, fl);
        int s = gn >> 9;                  // 0:q 1:k 2:v
        int hh = (gn >> 5) & 15;
        int d = gn & 31;
        #pragma unroll
        for (int i = 0; i < 4; ++i) {
            int gm0 = m0 + wv * 64 + i * 16 + kc * 4;   // %4==0; group all-in or all-out
            if (gm0 >= M) continue;
            int b = gm0 / NQ;
            int nn = gm0 - b * NQ;                      // %4==0, no b-straddle in group
            size_t bh = (size_t)(b * 16 + hh);
            if (s == 2) {
                uint2 u = pk4(acc[i][j][0] + bv, acc[i][j][1] + bv,
                              acc[i][j][2] + bv, acc[i][j][3] + bv);
                *(uint2*)(void*)(Vtw + (bh * HD + d) * VSTRIDE + nn) = u;
            } else if (s == 0) {
                #pragma unroll
                for (int r = 0; r < 4; ++r)
                    Qw[(bh * NQ + nn + r) * HD + d] = __hip_bfloat16((acc[i][j][r] + bv) * QS2);
            } else {
                #pragma unroll
                for (int r = 0; r < 4; ++r)
                    Kw[(bh * NQ + nn + r) * HD + d] = __hip_bfloat16(acc[i][j][r] + bv);
            }
        }
    }
}

// ---------------- m97-style 128x128 bf16 GEMM (proj): Out = A @ Bt^T + bias ---
__global__ __launch_bounds__(256) void gemm_bt(
    const __hip_bfloat16* __restrict__ A,
    const __hip_bfloat16* __restrict__ Bt,
    const void* __restrict__ biasv,
    int M,
    __hip_bfloat16* __restrict__ Out,
    float* __restrict__ OutF,
    const int* __restrict__ flag) {
    __shared__ __attribute__((aligned(16))) short sA[128 * 32];
    __shared__ __attribute__((aligned(16))) short sB[128 * 32];
    const int tid = threadIdx.x;
    const int lane = tid & 63;
    const int wv = tid >> 6;
    const int wr = wv >> 1, wc = wv & 1;
    const int lr = lane & 15, kc = lane >> 4;
    const int m0 = blockIdx.x * 128;
    const int n0 = blockIdx.y * 128;
    const int fl = *flag;

    f32x4 acc[4][4] = {};

    for (int k0 = 0; k0 < KDIM; k0 += 32) {
        #pragma unroll
        for (int it = 0; it < 2; ++it) {
            int idx = it * 256 + tid;           // 16-byte unit index
            int r = idx >> 2;
            int c = idx & 3;
            int gr = m0 + r; if (gr > M - 1) gr = M - 1;
            gld_lds16(A + (size_t)gr * KDIM + k0 + c * 8, (char*)sA + idx * 16);
            gld_lds16(Bt + (size_t)(n0 + r) * KDIM + k0 + c * 8, (char*)sB + idx * 16);
        }
        __syncthreads();
        short8 af[4], bfr[4];
        #pragma unroll
        for (int t = 0; t < 4; ++t)
            af[t] = *(const short8*)&sA[(wr * 64 + t * 16 + lr) * 32 + kc * 8];
        #pragma unroll
        for (int t = 0; t < 4; ++t)
            bfr[t] = *(const short8*)&sB[(wc * 64 + t * 16 + lr) * 32 + kc * 8];
        #pragma unroll
        for (int i = 0; i < 4; ++i)
            #pragma unroll
            for (int j = 0; j < 4; ++j)
                acc[i][j] = __builtin_amdgcn_mfma_f32_16x16x32_bf16(af[i], bfr[j], acc[i][j], 0, 0, 0);
        __syncthreads();
    }

    #pragma unroll
    for (int i = 0; i < 4; ++i) {
        #pragma unroll
        for (int j = 0; j < 4; ++j) {
            int gn = n0 + wc * 64 + j * 16 + lr;
            float bv = ldf(biasv, gn, fl);
            #pragma unroll
            for (int r = 0; r < 4; ++r) {
                int gm = m0 + wr * 64 + i * 16 + kc * 4 + r;
                if (gm < M) {
                    float v = acc[i][j][r] + bv;
                    if (fl) OutF[(size_t)gm * CD + gn] = v;
                    else    Out[(size_t)gm * CD + gn] = __hip_bfloat16(v);
                }
            }
        }
    }
}

// ------- fused attention v3: one WAVE per (bh, 32-row q-pair), no barriers ----
__global__ __launch_bounds__(256) void attn_k(
    const __hip_bfloat16* __restrict__ Qw,
    const __hip_bfloat16* __restrict__ Kw,
    const __hip_bfloat16* __restrict__ Vtw,
    const __hip_bfloat16* __restrict__ biasT,
    __hip_bfloat16* __restrict__ AO) {
    __shared__ __attribute__((aligned(16))) __hip_bfloat16 Pt[4][32 * PTS];

    const int tid = threadIdx.x;
    const int wv = tid >> 6;
    const int pair = blockIdx.x * 4 + wv;    // 0..23 exactly
    const int bh = blockIdx.y;               // b*16 + h
    const int hh = bh & 15;
    const int b = bh >> 4;
    const int q0 = pair * 32;
    const int lane = tid & 63;
    const int lr = lane & 15, kc = lane >> 4;

    const __hip_bfloat16* Qb = Qw + (size_t)bh * NQ * HD;
    const __hip_bfloat16* Kb = Kw + (size_t)bh * NQ * HD;
    const __hip_bfloat16* Vb = Vtw + (size_t)bh * HD * VSTRIDE;
    __hip_bfloat16* Pw = &Pt[wv][0];

    int qrA = q0 + lr;      if (qrA > NQ - 1) qrA = NQ - 1;
    int qrB = q0 + 16 + lr; if (qrB > NQ - 1) qrB = NQ - 1;
    short8 qfA = *(const short8*)(const void*)(Qb + qrA * HD + kc * 8);
    short8 qfB = *(const short8*)(const void*)(Qb + qrB * HD + kc * 8);

    short8 onesf;
    {
        short s1 = (lr == 0) ? (short)0x3F80 : (short)0;
        #pragma unroll
        for (int j = 0; j < 8; ++j) onesf[j] = s1;
    }

    const __hip_bfloat16* bt0 = biasT + (size_t)(hh * NQT + 2 * pair) * 768 * 16;
    const __hip_bfloat16* bt1 = bt0 + 768 * 16;

    f32x4 oa0 = {}, ob0 = {}, ol0 = {};
    f32x4 oa1 = {}, ob1 = {}, ol1 = {};

    for (int ks = 0; ks < 24; ++ks) {
        const int k0 = ks * 32;
        int kr0 = k0 + lr;      if (kr0 > NQ - 1) kr0 = NQ - 1;
        int kr1 = k0 + 16 + lr; if (kr1 > NQ - 1) kr1 = NQ - 1;
        short8 kf0 = *(const short8*)(const void*)(Kb + kr0 * HD + kc * 8);
        short8 kf1 = *(const short8*)(const void*)(Kb + kr1 * HD + kc * 8);
        short8 vf0 = *(const short8*)(const void*)(Vb + (size_t)lr * VSTRIDE + k0 + kc * 8);
        short8 vf1 = *(const short8*)(const void*)(Vb + (size_t)(lr + 16) * VSTRIDE + k0 + kc * 8);

        f32x4 c0 = bias4(bt0 + ((k0 + lr) * 16 + kc * 4));
        f32x4 c1 = bias4(bt0 + ((k0 + 16 + lr) * 16 + kc * 4));
        f32x4 c2 = bias4(bt1 + ((k0 + lr) * 16 + kc * 4));
        f32x4 c3 = bias4(bt1 + ((k0 + 16 + lr) * 16 + kc * 4));

        c0 = __builtin_amdgcn_mfma_f32_16x16x32_bf16(qfA, kf0, c0, 0, 0, 0);
        c1 = __builtin_amdgcn_mfma_f32_16x16x32_bf16(qfA, kf1, c1, 0, 0, 0);
        c2 = __builtin_amdgcn_mfma_f32_16x16x32_bf16(qfB, kf0, c2, 0, 0, 0);
        c3 = __builtin_amdgcn_mfma_f32_16x16x32_bf16(qfB, kf1, c3, 0, 0, 0);

        #pragma unroll
        for (int r = 0; r < 4; ++r) {
            c0[r] = fexp2(c0[r]); c1[r] = fexp2(c1[r]);
            c2[r] = fexp2(c2[r]); c3[r] = fexp2(c3[r]);
        }
        pkstore(Pw + lr * PTS + kc * 4, c0);
        pkstore(Pw + (lr + 16) * PTS + kc * 4, c1);
        pkstore(Pw + lr * PTS + 16 + kc * 4, c2);
        pkstore(Pw + (lr + 16) * PTS + 16 + kc * 4, c3);
        asm volatile("" ::: "memory");
        __builtin_amdgcn_s_waitcnt(0xc07f);   // lgkmcnt(0); same-wave DS in order
        asm volatile("" ::: "memory");

        short8 pfA, pfB;
        #pragma unroll
        for (int j = 0; j < 8; ++j) {
            pfA[j] = ((const short*)Pw)[(kc * 8 + j) * PTS + lr];
            pfB[j] = ((const short*)Pw)[(kc * 8 + j) * PTS + 16 + lr];
        }
        oa0 = __builtin_amdgcn_mfma_f32_16x16x32_bf16(pfA, vf0, oa0, 0, 0, 0);
        ob0 = __builtin_amdgcn_mfma_f32_16x16x32_bf16(pfA, vf1, ob0, 0, 0, 0);
        ol0 = __builtin_amdgcn_mfma_f32_16x16x32_bf16(pfA, onesf, ol0, 0, 0, 0);
        oa1 = __builtin_amdgcn_mfma_f32_16x16x32_bf16(pfB, vf0, oa1, 0, 0, 0);
        ob1 = __builtin_amdgcn_mfma_f32_16x16x32_bf16(pfB, vf1, ob1, 0, 0, 0);
        ol1 = __builtin_amdgcn_mfma_f32_16x16x32_bf16(pfB, onesf, ol1, 0, 0, 0);
    }

    #pragma unroll
    for (int r = 0; r < 4; ++r) {
        int row = kc * 4 + r;
        float lA = __shfl(ol0[r], lane & 48);
        float lB = __shfl(ol1[r], lane & 48);
        float liA = 1.0f / lA, liB = 1.0f / lB;
        int orA = q0 + row, orB = q0 + 16 + row;
        if (orA < NQ) {
            size_t base = ((size_t)b * NQ + orA) * CD + hh * HD;
            AO[base + lr]      = __hip_bfloat16(oa0[r] * liA);
            AO[base + 16 + lr] = __hip_bfloat16(ob0[r] * liA);
        }
        if (orB < NQ) {
            size_t base = ((size_t)b * NQ + orB) * CD + hh * HD;
            AO[base + lr]      = __hip_bfloat16(oa1[r] * liB);
            AO[base + 16 + lr] = __hip_bfloat16(ob1[r] * liB);
        }
    }
}

extern "C" void kernel_launch(void* const* d_in, const int* in_sizes, int n_in,
                              void* d_out, int out_size, void* d_ws, size_t ws_size,
                              hipStream_t stream) {
    char* ws = (char*)d_ws;
    size_t off = 0;
    auto carve = [&](size_t bytes) {
        char* p = ws + off;
        off += (bytes + 255) & ~(size_t)255;
        return p;
    };
    int* flagp = (int*)carve(256);
    __hip_bfloat16* Qw    = (__hip_bfloat16*)carve((size_t)256 * NQ * HD * 2);
    __hip_bfloat16* Kw    = (__hip_bfloat16*)carve((size_t)256 * NQ * HD * 2);
    __hip_bfloat16* Vtw   = (__hip_bfloat16*)carve((size_t)256 * HD * VSTRIDE * 2);
    __hip_bfloat16* WqT   = (__hip_bfloat16*)carve((size_t)1536 * 512 * 2);
    __hip_bfloat16* WpT   = (__hip_bfloat16*)carve((size_t)512 * 512 * 2);
    __hip_bfloat16* biasT = (__hip_bfloat16*)carve((size_t)16 * NQT * 768 * 16 * 2);
    __hip_bfloat16* Xb    = (__hip_bfloat16*)carve((size_t)MROWS * CD * 2);
    __hip_bfloat16* AO    = Xb;   // attn output overwrites x-staging (dead after qkv gemm)
    (void)ws_size; (void)in_sizes; (void)n_in; (void)out_size;

    sniff_k<<<dim3(1), dim3(64), 0, stream>>>((const unsigned int*)d_in[1], flagp);
    convx_k<<<dim3(5920), dim3(256), 0, stream>>>(d_in[0], (ushort4*)Xb, MROWS * CD / 4, flagp);
    transpose_k<<<dim3(48, 16), dim3(32, 8), 0, stream>>>(d_in[1], WqT, 512, 1536, flagp);
    transpose_k<<<dim3(16, 16), dim3(32, 8), 0, stream>>>(d_in[3], WpT, 512, 512, flagp);
    biasT_k<<<dim3(16 * NQT), dim3(256), 0, stream>>>(d_in[5], d_in[6], d_in[7], d_in[8],
                                                      d_in[9], d_in[10], biasT, flagp);
    gemm_qkv<<<dim3(47, 12), dim3(256), 0, stream>>>(Xb, WqT, d_in[2],
        Qw, Kw, Vtw, flagp);
    attn_k<<<dim3(6, 256), dim3(256), 0, stream>>>(Qw, Kw, Vtw, biasT, AO);
    gemm_bt<<<dim3(93, 4), dim3(256), 0, stream>>>(AO, WpT, d_in[4], MROWS,
        (__hip_bfloat16*)d_out, (float*)d_out, flagp);
}